// Round 1
// baseline (157.030 us; speedup 1.0000x reference)
//
#include <hip/hip_runtime.h>
#include <hip/hip_bf16.h>
#include <math.h>

// ---- static config ----
#define B_     8
#define CIN_   32
#define COUT_  32
#define H_     256
#define W_     256
#define K_     36
#define P_     3
#define KW_    7
#define TAPS_  49
#define EPS_   1e-5f
#define SLOPE_ 0.2f

// ws layout:
//   bytes [0 .. 100352)            kerB (ushort bf16) [2 g16][49 tap][64 lane][8]
//   bytes [102400 .. 102400+512K)  partials float2 [256 bo][256 tile]
#define PART_OFF_F  25600   // float offset of partials (float2 entries)

// Img_s: fp32, 4 planes [ci>>2][20 py][21 px (20 used + pad col)][4 ci]
// row stride 336 B (21 groups of 16B, 21%8=5) and plane 6736 B (421 groups,
// 421%8=5) break the bank aliasing of rows-2-apart / plane-pairs.
#define IMG_PLANE_B   6736
#define IMG_ROW_B     336

using short8_t  = __attribute__((ext_vector_type(8)))  short;
using f32x16_t  = __attribute__((ext_vector_type(16))) float;
using f32x4_t   = __attribute__((ext_vector_type(4)))  float;

// Xup bank swizzle (validated r5-r8): XOR byte-addr bit7 into bit4
#define SWZ(a) ((a) ^ ((((a) >> 7) & 1) << 4))

__device__ inline ushort f32_to_bf16(float f) {
    unsigned int bits = __float_as_uint(f);
    unsigned int r = (bits + 0x7FFFu + ((bits >> 16) & 1u)) >> 16;
    return (ushort)r;
}

// ============================================================
// Kernel A: build pre-swizzled B-fragments (unchanged, validated).
// ============================================================
__global__ __launch_bounds__(256)
void build_kernel(const float* __restrict__ weight, ushort* __restrict__ kerB) {
    __shared__ float psi_s[K_];
    const int tap = blockIdx.x;
    const int ty  = tap / KW_;
    const int tx  = tap % KW_;
    const int tid = threadIdx.x;

    if (tid < K_) {
        const double dxy   = 2.0 / 512.0;
        const double rcut  = 0.015;           // RADIUS_CUTOFF / 2
        const int    nr    = 6, nphi = 7;
        const double dr    = rcut / nr;
        const double dphi  = 2.0 * M_PI / nphi;
        const double norm  = M_PI * (rcut * nr / (nr + 1)) * (rcut * nr / (nr + 1));
        const double q     = dxy * dxy;

        const double offy = (double)(ty - P_) * dxy;
        const double offx = (double)(tx - P_) * dxy;
        const double r    = sqrt(offx * offx + offy * offy);
        double phi = atan2(offy, offx);
        if (phi < 0.0) phi += 2.0 * M_PI;

        const int k = tid;
        double ir, iphi;
        if (k == 0) { ir = 0.0; iphi = 0.0; }
        else        { ir = (double)((k - 1) / nphi + 1) * dr;
                      iphi = (double)((k - 1) % nphi) * dphi; }

        double rv = 1.0 - fabs(r - ir) / dr;
        rv = rv > 0.0 ? rv : 0.0;
        if (r > rcut) rv = 0.0;

        double pv = 1.0;
        if (k > 0) {
            double da = fabs(phi - iphi);
            double dm = da < (2.0 * M_PI - da) ? da : (2.0 * M_PI - da);
            pv = 1.0 - dm / dphi;
            pv = pv > 0.0 ? pv : 0.0;
        }
        psi_s[k] = (float)(rv * pv * q / norm);
    }
    __syncthreads();

    for (int e = tid; e < 1024; e += 256) {
        const int g16  = e >> 9;
        const int lane = (e >> 3) & 63;
        const int j    = e & 7;
        const int o    = lane & 31;
        const int ci   = g16 * 16 + ((lane >> 5) & 1) * 8 + j;
        const float* w = weight + (size_t)(o * CIN_ + ci) * K_;
        float s = 0.f;
        #pragma unroll
        for (int k = 0; k < K_; ++k) s = fmaf(w[k], psi_s[k], s);
        kerB[((size_t)(g16 * 49 + tap) * 64 + lane) * 8 + j] = f32_to_bf16(s);
    }
}

// ============================================================
// Kernel B: fused upsample + implicit-GEMM conv + stats partials.
// grid = (16,16,B), block = 512 (8 waves). Tile = 16x16 pixels x 32 cout.
// r9: stage 2 rewritten as separable closed-form polyphase upsample.
//   align_corners 2x scale has exact structure: ry = y>>1 and
//   wy = ((y&1)?510:255 - (R0+ry))/511 with unclamped patch origin
//   R0 = i0-2 and zero-filled guard rows/cols. Each thread owns
//   (gsub, y, 6-wide x chunk): y-lerps 4 columns x 2 planes once into
//   registers, then 6 x-lerps. 2.6x less stage-2 LDS read traffic,
//   ~1.8x fewer lerp ops, no tables / per-entry div.
// ============================================================
__global__ __launch_bounds__(512, 4)
void conv_mfma(const float* __restrict__ image,
               const ushort* __restrict__ kerB,
               float* __restrict__ out,
               float* __restrict__ partials) {
    __shared__ float  Img_s[6736];            // 26944 B (4 planes x 6736 B)
    __shared__ ushort Xup_s[2738 * 8];        // 43808 B
    __shared__ float  wp[8][32][2];           // per-wave stats partials

    const int tid  = threadIdx.x;
    const int lane = tid & 63;
    const int w    = tid >> 6;                // wave 0..7 = M-tile index
    const int j0 = blockIdx.x * 16;
    const int i0 = blockIdx.y * 16;
    const int b  = blockIdx.z;

    const int u0 = 2 * i0 - 3;
    const int v0 = 2 * j0 - 3;
    const int R0 = i0 - 2;                    // unclamped patch origin (rows)
    const int C0 = j0 - 2;                    // unclamped patch origin (cols)

    // A-fragment lane mapping (32x32x16): m = lane&31, k-half gs = lane>>5
    const int gs  = lane >> 5;
    const int tio = (lane & 31) >> 4;         // pixel-row parity within M-tile
    const int tj  = lane & 15;                // pixel col
    const int yb0 = 4 * w + 2 * tio;          // Xup row base for this lane
    const int xb  = 2 * tj;

    f32x16_t acc;
    #pragma unroll
    for (int q = 0; q < 16; ++q) acc[q] = 0.f;

    char* img_bytes = (char*)Img_s;
    char* xup_bytes = (char*)Xup_s;

    for (int g16 = 0; g16 < 2; ++g16) {
        // ---- stage 1: 20x20 patch, 4ci granules, zero-filled guards ----
        const float* img = image + (size_t)(b * CIN_ + g16 * 16) * (H_ * W_);
        for (int e = tid; e < 1600; e += 512) {
            const int p  = e / 400;                  // ci quad (plane)
            const int yx = e - p * 400;
            const int py = yx / 20, px = yx - py * 20;
            const int row = R0 + py, col = C0 + px;
            f32x4_t g = {0.f, 0.f, 0.f, 0.f};
            if ((unsigned)row < 256u && (unsigned)col < 256u) {
                const float* q = img + (size_t)p * 4 * (H_ * W_) + row * W_ + col;
                g[0] = q[0];
                g[1] = q[H_ * W_];
                g[2] = q[2 * H_ * W_];
                g[3] = q[3 * H_ * W_];
            }
            *(f32x4_t*)(img_bytes + p * IMG_PLANE_B + (py * 21 + px) * 16) = g;
        }
        __syncthreads();

        // ---- stage 2: separable closed-form upsample ----
        // item e -> (gsub g, y 0..36, chunk c 0..6); chunk covers x0..x0+5.
        for (int e = tid; e < 518; e += 512) {
            const int g   = (e >= 259) ? 1 : 0;
            const int r   = e - 259 * g;
            const int y   = r / 7;
            const int c   = r - 7 * y;
            const int x0  = 6 * c;
            const int ry  = y >> 1;
            const int Ay  = R0 + ry;
            const float wy = (float)(((y & 1) ? 510 : 255) - Ay) * (1.0f / 511.0f);
            const bool oky = ((unsigned)(u0 + y) < 512u);

            const char* lo = img_bytes + (2 * g) * IMG_PLANE_B
                           + (ry * 21 + (x0 >> 1)) * 16;
            const char* hi = lo + IMG_PLANE_B;
            f32x4_t colA[4], colB[4];
            #pragma unroll
            for (int k = 0; k < 4; ++k) {
                const f32x4_t a0 = *(const f32x4_t*)(lo + k * 16);
                const f32x4_t a1 = *(const f32x4_t*)(lo + k * 16 + IMG_ROW_B);
                colA[k] = a0 + wy * (a1 - a0);
                const f32x4_t b0 = *(const f32x4_t*)(hi + k * 16);
                const f32x4_t b1 = *(const f32x4_t*)(hi + k * 16 + IMG_ROW_B);
                colB[k] = b0 + wy * (b1 - b0);
            }

            const int base_idx = g * 1369 + y * 37;
            #pragma unroll
            for (int m = 0; m < 6; ++m) {
                const int x = x0 + m;
                if (x < 37) {
                    const int cx = m >> 1;            // 0,0,1,1,2,2 (static)
                    const int Ax = C0 + (x >> 1);
                    const float wx =
                        (float)(((x & 1) ? 510 : 255) - Ax) * (1.0f / 511.0f);
                    const f32x4_t va = colA[cx] + wx * (colA[cx + 1] - colA[cx]);
                    const f32x4_t vb = colB[cx] + wx * (colB[cx + 1] - colB[cx]);
                    const bool ok = oky && ((unsigned)(v0 + x) < 512u);
                    __hip_bfloat162 h0 = __float22bfloat162_rn(make_float2(va[0], va[1]));
                    __hip_bfloat162 h1 = __float22bfloat162_rn(make_float2(va[2], va[3]));
                    __hip_bfloat162 h2 = __float22bfloat162_rn(make_float2(vb[0], vb[1]));
                    __hip_bfloat162 h3 = __float22bfloat162_rn(make_float2(vb[2], vb[3]));
                    union { short8_t s8; uint4 u4; } pk;
                    pk.u4.x = ok ? *(unsigned int*)&h0 : 0u;
                    pk.u4.y = ok ? *(unsigned int*)&h1 : 0u;
                    pk.u4.z = ok ? *(unsigned int*)&h2 : 0u;
                    pk.u4.w = ok ? *(unsigned int*)&h3 : 0u;
                    const int addr = SWZ((base_idx + x) << 4);
                    *(short8_t*)(xup_bytes + addr) = pk.s8;
                }
            }
        }
        __syncthreads();

        // ---- stage 3: 49 taps x 1 MFMA per wave, ky-chunked bfrag prefetch ----
        const ushort* kbp = kerB + ((size_t)(g16 * 49 * 64 + lane)) * 8;
        #pragma unroll
        for (int ky = 0; ky < KW_; ++ky) {
            short8_t bf[KW_];
            #pragma unroll
            for (int kx = 0; kx < KW_; ++kx)
                bf[kx] = *(const short8_t*)(kbp + (size_t)(ky * KW_ + kx) * 512);
            const int rowbase = (gs * 1369 + (yb0 + ky) * 37 + xb) << 4;
            #pragma unroll
            for (int kx = 0; kx < KW_; ++kx) {
                const int a0 = SWZ(rowbase + (kx << 4));
                const short8_t afrag = *(const short8_t*)(xup_bytes + a0);
                acc = __builtin_amdgcn_mfma_f32_32x32x16_bf16(afrag, bf[kx], acc, 0, 0, 0);
            }
        }
        __syncthreads();   // before next group's staging overwrites LDS
    }

    // ---- epilogue: C-writes (layout col n=lane&31, row m=(q&3)+8*(q>>2)+4*gs)
    const int n = lane & 31;
    float* op = out + (size_t)(b * COUT_ + n) * (H_ * W_);
    const int ibase = i0 + 2 * w;
    #pragma unroll
    for (int grp = 0; grp < 4; ++grp) {
        const int ti  = ibase + (grp >> 1);
        const int tjj = j0 + ((grp & 1) ? 8 : 0) + 4 * gs;
        f32x4_t s;
        s[0] = acc[grp * 4 + 0]; s[1] = acc[grp * 4 + 1];
        s[2] = acc[grp * 4 + 2]; s[3] = acc[grp * 4 + 3];
        *(f32x4_t*)(op + (size_t)ti * W_ + tjj) = s;
    }

    // ---- epilogue: InstanceNorm partial sums from registers ----
    float s1 = 0.f, s2 = 0.f;
    #pragma unroll
    for (int q = 0; q < 16; ++q) { s1 += acc[q]; s2 = fmaf(acc[q], acc[q], s2); }
    s1 += __shfl_xor(s1, 32);
    s2 += __shfl_xor(s2, 32);
    if (lane < 32) { wp[w][lane][0] = s1; wp[w][lane][1] = s2; }
    __syncthreads();
    if (tid < 32) {
        float t1 = 0.f, t2 = 0.f;
        #pragma unroll
        for (int wv = 0; wv < 8; ++wv) { t1 += wp[wv][tid][0]; t2 += wp[wv][tid][1]; }
        const int tile = blockIdx.y * 16 + blockIdx.x;
        float2* pp = (float2*)partials;
        pp[((b * 32 + tid) << 8) | tile] = make_float2(t1, t2);
    }
}

// ============================================================
// Kernel C: per-block stats reduce + normalize + LeakyReLU.
// grid = 16384, block = 256. Each block: reduce 256 tile-partials of its
// (b,o) channel (fixed-order tree -> deterministic), then 256 float4s.
// ============================================================
__global__ __launch_bounds__(256)
void norm2_kernel(float* __restrict__ y, const float* __restrict__ partials) {
    __shared__ float r1[256];
    __shared__ float r2[256];
    const int tid = threadIdx.x;
    const int blk = blockIdx.x;
    const int bo  = blk >> 6;                  // 64 blocks per channel
    const float2 p = ((const float2*)partials)[(bo << 8) | tid];
    r1[tid] = p.x; r2[tid] = p.y;
    __syncthreads();
    for (int off = 128; off > 0; off >>= 1) {
        if (tid < off) { r1[tid] += r1[tid + off]; r2[tid] += r2[tid + off]; }
        __syncthreads();
    }
    const float inv = 1.0f / 65536.0f;
    const float m   = r1[0] * inv;
    const float var = r2[0] * inv - m * m;
    const float rs  = 1.0f / sqrtf(var + EPS_);

    const int e = blk * 256 + tid;             // float4 index
    float4 v = ((const float4*)y)[e];
    v.x = (v.x - m) * rs; v.x = v.x >= 0.f ? v.x : SLOPE_ * v.x;
    v.y = (v.y - m) * rs; v.y = v.y >= 0.f ? v.y : SLOPE_ * v.y;
    v.z = (v.z - m) * rs; v.z = v.z >= 0.f ? v.z : SLOPE_ * v.z;
    v.w = (v.w - m) * rs; v.w = v.w >= 0.f ? v.w : SLOPE_ * v.w;
    ((float4*)y)[e] = v;
}

// ============================================================
extern "C" void kernel_launch(void* const* d_in, const int* in_sizes, int n_in,
                              void* d_out, int out_size, void* d_ws, size_t ws_size,
                              hipStream_t stream) {
    const float* image  = (const float*)d_in[0];
    const float* weight = (const float*)d_in[1];
    float*  out      = (float*)d_out;
    ushort* kerB     = (ushort*)d_ws;
    float*  partials = (float*)d_ws + PART_OFF_F;

    build_kernel<<<dim3(TAPS_), dim3(256), 0, stream>>>(weight, kerB);
    conv_mfma<<<dim3(16, 16, B_), dim3(512), 0, stream>>>(image, kerB, out, partials);
    norm2_kernel<<<dim3(16384), dim3(256), 0, stream>>>(out, partials);
}

// Round 2
// 127.650 us; speedup vs baseline: 1.2302x; 1.2302x over previous
//
#include <hip/hip_runtime.h>
#include <hip/hip_bf16.h>
#include <math.h>

// ---- static config ----
#define B_     8
#define CIN_   32
#define COUT_  32
#define H_     256
#define W_     256
#define K_     36
#define P_     3
#define KW_    7
#define TAPS_  49
#define EPS_   1e-5f
#define SLOPE_ 0.2f

// ws layout:
//   bytes [0 .. 100352)            kerB (ushort bf16) [2 g16][49 tap][64 lane][8]
//   bytes [102400 .. 102400+512K)  partials float2 [256 bo][256 tile]
#define PART_OFF_F  25600   // float offset of partials (float2 entries)

// Img_s: fp32, 4 planes [ci>>2][20 py][21 px (20 used + pad col)][4 ci]
// row stride 336 B (21 groups of 16B, 21%8=5) and plane 6736 B (421 groups,
// 421%8=5) break the bank aliasing of rows-2-apart / plane-pairs.
#define IMG_PLANE_B   6736
#define IMG_ROW_B     336

using short8_t  = __attribute__((ext_vector_type(8)))  short;
using f32x16_t  = __attribute__((ext_vector_type(16))) float;
using f32x4_t   = __attribute__((ext_vector_type(4)))  float;

// Xup bank swizzle (validated r5-r8): XOR byte-addr bit7 into bit4
#define SWZ(a) ((a) ^ ((((a) >> 7) & 1) << 4))

__device__ inline ushort f32_to_bf16(float f) {
    unsigned int bits = __float_as_uint(f);
    unsigned int r = (bits + 0x7FFFu + ((bits >> 16) & 1u)) >> 16;
    return (ushort)r;
}

// ============================================================
// Kernel A: build pre-swizzled B-fragments (unchanged, validated).
// ============================================================
__global__ __launch_bounds__(256)
void build_kernel(const float* __restrict__ weight, ushort* __restrict__ kerB) {
    __shared__ float psi_s[K_];
    const int tap = blockIdx.x;
    const int ty  = tap / KW_;
    const int tx  = tap % KW_;
    const int tid = threadIdx.x;

    if (tid < K_) {
        const double dxy   = 2.0 / 512.0;
        const double rcut  = 0.015;           // RADIUS_CUTOFF / 2
        const int    nr    = 6, nphi = 7;
        const double dr    = rcut / nr;
        const double dphi  = 2.0 * M_PI / nphi;
        const double norm  = M_PI * (rcut * nr / (nr + 1)) * (rcut * nr / (nr + 1));
        const double q     = dxy * dxy;

        const double offy = (double)(ty - P_) * dxy;
        const double offx = (double)(tx - P_) * dxy;
        const double r    = sqrt(offx * offx + offy * offy);
        double phi = atan2(offy, offx);
        if (phi < 0.0) phi += 2.0 * M_PI;

        const int k = tid;
        double ir, iphi;
        if (k == 0) { ir = 0.0; iphi = 0.0; }
        else        { ir = (double)((k - 1) / nphi + 1) * dr;
                      iphi = (double)((k - 1) % nphi) * dphi; }

        double rv = 1.0 - fabs(r - ir) / dr;
        rv = rv > 0.0 ? rv : 0.0;
        if (r > rcut) rv = 0.0;

        double pv = 1.0;
        if (k > 0) {
            double da = fabs(phi - iphi);
            double dm = da < (2.0 * M_PI - da) ? da : (2.0 * M_PI - da);
            pv = 1.0 - dm / dphi;
            pv = pv > 0.0 ? pv : 0.0;
        }
        psi_s[k] = (float)(rv * pv * q / norm);
    }
    __syncthreads();

    for (int e = tid; e < 1024; e += 256) {
        const int g16  = e >> 9;
        const int lane = (e >> 3) & 63;
        const int j    = e & 7;
        const int o    = lane & 31;
        const int ci   = g16 * 16 + ((lane >> 5) & 1) * 8 + j;
        const float* w = weight + (size_t)(o * CIN_ + ci) * K_;
        float s = 0.f;
        #pragma unroll
        for (int k = 0; k < K_; ++k) s = fmaf(w[k], psi_s[k], s);
        kerB[((size_t)(g16 * 49 + tap) * 64 + lane) * 8 + j] = f32_to_bf16(s);
    }
}

// ============================================================
// Kernel B: fused upsample + implicit-GEMM conv + stats partials.
// grid = (16,16,B), block = 512 (8 waves). Tile = 16x16 pixels x 32 cout.
// r10: stage 2 = r8 item structure (named scalars only, no indexed
// arrays -> no scratch) + closed-form polyphase weights (no tables) +
// even/odd x-PAIR per item: outputs x=2c,2c+1 share source columns
// c,c+1 and the y-lerp, so 8 LDS reads produce 2 outputs (was 8 reads
// per 1 output in r8, plus 4 table reads). Halves stage-2 LDS traffic.
// ============================================================
__global__ __launch_bounds__(512, 4)
void conv_mfma(const float* __restrict__ image,
               const ushort* __restrict__ kerB,
               float* __restrict__ out,
               float* __restrict__ partials) {
    __shared__ float  Img_s[6736];            // 26944 B (4 planes x 6736 B)
    __shared__ ushort Xup_s[2738 * 8];        // 43808 B
    __shared__ float  wp[8][32][2];           // per-wave stats partials

    const int tid  = threadIdx.x;
    const int lane = tid & 63;
    const int w    = tid >> 6;                // wave 0..7 = M-tile index
    const int j0 = blockIdx.x * 16;
    const int i0 = blockIdx.y * 16;
    const int b  = blockIdx.z;

    const int u0 = 2 * i0 - 3;
    const int v0 = 2 * j0 - 3;
    const int R0 = i0 - 2;                    // unclamped patch origin (rows)
    const int C0 = j0 - 2;                    // unclamped patch origin (cols)

    // A-fragment lane mapping (32x32x16): m = lane&31, k-half gs = lane>>5
    const int gs  = lane >> 5;
    const int tio = (lane & 31) >> 4;         // pixel-row parity within M-tile
    const int tj  = lane & 15;                // pixel col
    const int yb0 = 4 * w + 2 * tio;          // Xup row base for this lane
    const int xb  = 2 * tj;

    f32x16_t acc;
    #pragma unroll
    for (int q = 0; q < 16; ++q) acc[q] = 0.f;

    char* img_bytes = (char*)Img_s;
    char* xup_bytes = (char*)Xup_s;

    for (int g16 = 0; g16 < 2; ++g16) {
        // ---- stage 1: 20x20 patch, 4ci granules, zero-filled guards ----
        const float* img = image + (size_t)(b * CIN_ + g16 * 16) * (H_ * W_);
        for (int e = tid; e < 1600; e += 512) {
            const int p  = e / 400;                  // ci quad (plane)
            const int yx = e - p * 400;
            const int py = yx / 20, px = yx - py * 20;
            const int row = R0 + py, col = C0 + px;
            f32x4_t g = {0.f, 0.f, 0.f, 0.f};
            if ((unsigned)row < 256u && (unsigned)col < 256u) {
                const float* q = img + (size_t)p * 4 * (H_ * W_) + row * W_ + col;
                g[0] = q[0];
                g[1] = q[H_ * W_];
                g[2] = q[2 * H_ * W_];
                g[3] = q[3 * H_ * W_];
            }
            *(f32x4_t*)(img_bytes + p * IMG_PLANE_B + (py * 21 + px) * 16) = g;
        }
        __syncthreads();

        // ---- stage 2: closed-form upsample, even/odd x-pair per item ----
        // item e -> (gsub g, y 0..36, xp 0..18); outputs x=2xp, 2xp+1.
        // align_corners 2x exact polyphase: ry = y>>1,
        // wy = ((y&1)?510:255 - (R0+ry)) / 511, same in x.
        for (int e = tid; e < 1406; e += 512) {
            const int g   = (e >= 703) ? 1 : 0;
            const int r   = e - 703 * g;
            const int y   = r / 19;
            const int xp  = r - 19 * y;
            const int x   = 2 * xp;
            const int ry  = y >> 1;
            const float wy =
                (float)((((y & 1) ? 510 : 255)) - (R0 + ry)) * (1.0f / 511.0f);
            const int Ax = C0 + xp;
            const float wx0 = (float)(255 - Ax) * (1.0f / 511.0f);
            const float wx1 = (float)(510 - Ax) * (1.0f / 511.0f);
            const bool oky = ((unsigned)(u0 + y) < 512u);
            const bool ok0 = oky && ((unsigned)(v0 + x) < 512u);
            const bool ok1 = oky && ((unsigned)(v0 + x + 1) < 512u);

            const char* lo = img_bytes + (2 * g) * IMG_PLANE_B
                           + (ry * 21 + xp) * 16;
            const char* hi = lo + IMG_PLANE_B;
            const f32x4_t a00 = *(const f32x4_t*)(lo);
            const f32x4_t a01 = *(const f32x4_t*)(lo + 16);
            const f32x4_t a10 = *(const f32x4_t*)(lo + IMG_ROW_B);
            const f32x4_t a11 = *(const f32x4_t*)(lo + IMG_ROW_B + 16);
            const f32x4_t b00 = *(const f32x4_t*)(hi);
            const f32x4_t b01 = *(const f32x4_t*)(hi + 16);
            const f32x4_t b10 = *(const f32x4_t*)(hi + IMG_ROW_B);
            const f32x4_t b11 = *(const f32x4_t*)(hi + IMG_ROW_B + 16);

            // shared y-lerp: two columns x two plane-halves
            const f32x4_t cA0 = a00 + wy * (a10 - a00);
            const f32x4_t cA1 = a01 + wy * (a11 - a01);
            const f32x4_t cB0 = b00 + wy * (b10 - b00);
            const f32x4_t cB1 = b01 + wy * (b11 - b01);

            const int idx = g * 1369 + y * 37 + x;

            // even output x
            {
                const f32x4_t va = cA0 + wx0 * (cA1 - cA0);
                const f32x4_t vb = cB0 + wx0 * (cB1 - cB0);
                __hip_bfloat162 h0 = __float22bfloat162_rn(make_float2(va[0], va[1]));
                __hip_bfloat162 h1 = __float22bfloat162_rn(make_float2(va[2], va[3]));
                __hip_bfloat162 h2 = __float22bfloat162_rn(make_float2(vb[0], vb[1]));
                __hip_bfloat162 h3 = __float22bfloat162_rn(make_float2(vb[2], vb[3]));
                union { short8_t s8; uint4 u4; } pk;
                pk.u4.x = ok0 ? *(unsigned int*)&h0 : 0u;
                pk.u4.y = ok0 ? *(unsigned int*)&h1 : 0u;
                pk.u4.z = ok0 ? *(unsigned int*)&h2 : 0u;
                pk.u4.w = ok0 ? *(unsigned int*)&h3 : 0u;
                *(short8_t*)(xup_bytes + SWZ(idx << 4)) = pk.s8;
            }
            // odd output x+1 (xp=18 -> x+1=37 is outside the row: skip store)
            if (x + 1 < 37) {
                const f32x4_t va = cA0 + wx1 * (cA1 - cA0);
                const f32x4_t vb = cB0 + wx1 * (cB1 - cB0);
                __hip_bfloat162 h0 = __float22bfloat162_rn(make_float2(va[0], va[1]));
                __hip_bfloat162 h1 = __float22bfloat162_rn(make_float2(va[2], va[3]));
                __hip_bfloat162 h2 = __float22bfloat162_rn(make_float2(vb[0], vb[1]));
                __hip_bfloat162 h3 = __float22bfloat162_rn(make_float2(vb[2], vb[3]));
                union { short8_t s8; uint4 u4; } pk;
                pk.u4.x = ok1 ? *(unsigned int*)&h0 : 0u;
                pk.u4.y = ok1 ? *(unsigned int*)&h1 : 0u;
                pk.u4.z = ok1 ? *(unsigned int*)&h2 : 0u;
                pk.u4.w = ok1 ? *(unsigned int*)&h3 : 0u;
                *(short8_t*)(xup_bytes + SWZ((idx + 1) << 4)) = pk.s8;
            }
        }
        __syncthreads();

        // ---- stage 3: 49 taps x 1 MFMA per wave, ky-chunked bfrag prefetch ----
        const ushort* kbp = kerB + ((size_t)(g16 * 49 * 64 + lane)) * 8;
        #pragma unroll
        for (int ky = 0; ky < KW_; ++ky) {
            short8_t bf[KW_];
            #pragma unroll
            for (int kx = 0; kx < KW_; ++kx)
                bf[kx] = *(const short8_t*)(kbp + (size_t)(ky * KW_ + kx) * 512);
            const int rowbase = (gs * 1369 + (yb0 + ky) * 37 + xb) << 4;
            #pragma unroll
            for (int kx = 0; kx < KW_; ++kx) {
                const int a0 = SWZ(rowbase + (kx << 4));
                const short8_t afrag = *(const short8_t*)(xup_bytes + a0);
                acc = __builtin_amdgcn_mfma_f32_32x32x16_bf16(afrag, bf[kx], acc, 0, 0, 0);
            }
        }
        __syncthreads();   // before next group's staging overwrites LDS
    }

    // ---- epilogue: C-writes (layout col n=lane&31, row m=(q&3)+8*(q>>2)+4*gs)
    const int n = lane & 31;
    float* op = out + (size_t)(b * COUT_ + n) * (H_ * W_);
    const int ibase = i0 + 2 * w;
    #pragma unroll
    for (int grp = 0; grp < 4; ++grp) {
        const int ti  = ibase + (grp >> 1);
        const int tjj = j0 + ((grp & 1) ? 8 : 0) + 4 * gs;
        f32x4_t s;
        s[0] = acc[grp * 4 + 0]; s[1] = acc[grp * 4 + 1];
        s[2] = acc[grp * 4 + 2]; s[3] = acc[grp * 4 + 3];
        *(f32x4_t*)(op + (size_t)ti * W_ + tjj) = s;
    }

    // ---- epilogue: InstanceNorm partial sums from registers ----
    float s1 = 0.f, s2 = 0.f;
    #pragma unroll
    for (int q = 0; q < 16; ++q) { s1 += acc[q]; s2 = fmaf(acc[q], acc[q], s2); }
    s1 += __shfl_xor(s1, 32);
    s2 += __shfl_xor(s2, 32);
    if (lane < 32) { wp[w][lane][0] = s1; wp[w][lane][1] = s2; }
    __syncthreads();
    if (tid < 32) {
        float t1 = 0.f, t2 = 0.f;
        #pragma unroll
        for (int wv = 0; wv < 8; ++wv) { t1 += wp[wv][tid][0]; t2 += wp[wv][tid][1]; }
        const int tile = blockIdx.y * 16 + blockIdx.x;
        float2* pp = (float2*)partials;
        pp[((b * 32 + tid) << 8) | tile] = make_float2(t1, t2);
    }
}

// ============================================================
// Kernel C: per-block stats reduce + normalize + LeakyReLU.
// grid = 16384, block = 256. Each block: reduce 256 tile-partials of its
// (b,o) channel (fixed-order tree -> deterministic), then 256 float4s.
// ============================================================
__global__ __launch_bounds__(256)
void norm2_kernel(float* __restrict__ y, const float* __restrict__ partials) {
    __shared__ float r1[256];
    __shared__ float r2[256];
    const int tid = threadIdx.x;
    const int blk = blockIdx.x;
    const int bo  = blk >> 6;                  // 64 blocks per channel
    const float2 p = ((const float2*)partials)[(bo << 8) | tid];
    r1[tid] = p.x; r2[tid] = p.y;
    __syncthreads();
    for (int off = 128; off > 0; off >>= 1) {
        if (tid < off) { r1[tid] += r1[tid + off]; r2[tid] += r2[tid + off]; }
        __syncthreads();
    }
    const float inv = 1.0f / 65536.0f;
    const float m   = r1[0] * inv;
    const float var = r2[0] * inv - m * m;
    const float rs  = 1.0f / sqrtf(var + EPS_);

    const int e = blk * 256 + tid;             // float4 index
    float4 v = ((const float4*)y)[e];
    v.x = (v.x - m) * rs; v.x = v.x >= 0.f ? v.x : SLOPE_ * v.x;
    v.y = (v.y - m) * rs; v.y = v.y >= 0.f ? v.y : SLOPE_ * v.y;
    v.z = (v.z - m) * rs; v.z = v.z >= 0.f ? v.z : SLOPE_ * v.z;
    v.w = (v.w - m) * rs; v.w = v.w >= 0.f ? v.w : SLOPE_ * v.w;
    ((float4*)y)[e] = v;
}

// ============================================================
extern "C" void kernel_launch(void* const* d_in, const int* in_sizes, int n_in,
                              void* d_out, int out_size, void* d_ws, size_t ws_size,
                              hipStream_t stream) {
    const float* image  = (const float*)d_in[0];
    const float* weight = (const float*)d_in[1];
    float*  out      = (float*)d_out;
    ushort* kerB     = (ushort*)d_ws;
    float*  partials = (float*)d_ws + PART_OFF_F;

    build_kernel<<<dim3(TAPS_), dim3(256), 0, stream>>>(weight, kerB);
    conv_mfma<<<dim3(16, 16, B_), dim3(512), 0, stream>>>(image, kerB, out, partials);
    norm2_kernel<<<dim3(16384), dim3(256), 0, stream>>>(out, partials);
}